// Round 1
// baseline (348.670 us; speedup 1.0000x reference)
//
#include <hip/hip_runtime.h>

#define LOG2PI 1.8378770664093453f

typedef float f4 __attribute__((ext_vector_type(4)));

// ---------------------------------------------------------------------------
// Fused OU log-prob, 2 batches per block. B=256, T=1024, D=256.
// Grid (8 t-chunks, B/2=128) = 1024 blocks = 4 blocks/CU;
// __launch_bounds__(256,4) -> 128-VGPR cap, ~16 waves/CU (2x prior TLP).
// Each wave owns ~32 consecutive transitions for TWO batches:
//   - ts row loaded once (L2-resident); dt/exp/q/log q computed once per pair
//   - y rows for 2 batches streamed non-temporally (each read exactly once)
//   - LOG2PI added analytically in the epilogue (term-count * LOG2PI)
// y_prev/ts_prev carried in registers; depth-1 load pipeline on 3 streams.
// ---------------------------------------------------------------------------
__global__ __launch_bounds__(256, 4) void ou_fused2_kernel(
    const float* __restrict__ y,    // B*T*D
    const float* __restrict__ ts,   // T*D
    const float* __restrict__ mu,   // D
    const float* __restrict__ lk,   // D
    const float* __restrict__ ls,   // D
    float* __restrict__ out,        // B
    int B, int T, int D)
{
    const int bp   = blockIdx.y * 2;           // first batch of this pair
    const int widx = threadIdx.x >> 6;
    const int lane = threadIdx.x & 63;
    const int d4   = lane * 4;                 // D == 256 == 64 lanes * 4
    const int NW   = gridDim.x * 4;            // waves per batch-pair (32)
    const int gw   = blockIdx.x * 4 + widx;
    const int NT   = T - 1;
    const int lo   = 1 + (NT * gw) / NW;
    const int hi   = 1 + (NT * (gw + 1)) / NW;

    // ---- per-d constants ----
    const f4 muv = *(const f4*)(mu + d4);
    const f4 lkv = *(const f4*)(lk + d4);
    const f4 lsv = *(const f4*)(ls + d4);
    float mur[4], kap[4], sv[4];               // sv = sigma^2 / (2 kappa)
    #pragma unroll
    for (int j = 0; j < 4; ++j) {
        mur[j] = muv[j];
        float xk = lkv[j];
        float kappa = fmaxf(xk, 0.0f) + log1pf(__expf(-fabsf(xk))) + 1e-6f;
        float xs = lsv[j];
        float sg = fmaxf(xs, 0.0f) + log1pf(__expf(-fabsf(xs))) + 1e-6f;
        kap[j] = kappa;
        sv[j]  = (sg * sg) * (0.5f / kappa);
    }

    // ---- boundary row t = lo-1 ----
    const float* yp[2];
    float tsp[4], yc[2][4];
    {
        const f4 t0 = *(const f4*)(ts + (size_t)(lo - 1) * D + d4);
        #pragma unroll
        for (int j = 0; j < 4; ++j) tsp[j] = t0[j];
        #pragma unroll
        for (int bb = 0; bb < 2; ++bb) {
            const size_t yb = (size_t)(bp + bb) * T * D;
            const f4 a = __builtin_nontemporal_load(
                (const f4*)(y + yb + (size_t)(lo - 1) * D + d4));
            #pragma unroll
            for (int j = 0; j < 4; ++j) yc[bb][j] = a[j] - mur[j];
            yp[bb] = y + yb + (size_t)lo * D + d4;
        }
    }

    float aq[2][4];                            // quadratic accum per batch
    #pragma unroll
    for (int bb = 0; bb < 2; ++bb)
        #pragma unroll
        for (int j = 0; j < 4; ++j) aq[bb][j] = 0.0f;
    float al[4] = {0, 0, 0, 0};                // log-det accum (shared)

    // ---- lp0 (global wave 0 owns row 0) ----
    if (gw == 0) {
        #pragma unroll
        for (int j = 0; j < 4; ++j) {
            float var0 = fmaxf(sv[j], 1e-10f);
            float iv   = __fdividef(1.0f, var0);
            al[j]     += __logf(var0);
            #pragma unroll
            for (int bb = 0; bb < 2; ++bb)
                aq[bb][j] += yc[bb][j] * yc[bb][j] * iv;
        }
    }

    // ---- main loop: depth-1 software pipeline on 3 streams ----
    const float* tp = ts + (size_t)lo * D + d4;
    f4 tc = *(const f4*)tp;
    f4 c0 = __builtin_nontemporal_load((const f4*)yp[0]);
    f4 c1 = __builtin_nontemporal_load((const f4*)yp[1]);

    for (int t = lo; t < hi; ++t) {
        f4 tn, n0, n1;
        if (t + 1 < hi) {
            tn = *(const f4*)(tp + D);
            n0 = __builtin_nontemporal_load((const f4*)(yp[0] + D));
            n1 = __builtin_nontemporal_load((const f4*)(yp[1] + D));
        }
        tp += D; yp[0] += D; yp[1] += D;

        #pragma unroll
        for (int j = 0; j < 4; ++j) {
            float dt = fmaxf(tc[j] - tsp[j], 1e-6f);
            tsp[j]   = tc[j];
            float e  = __expf(-kap[j] * dt);
            float q  = fmaxf(sv[j] * (1.0f - e * e), 1e-10f);
            float iq = __fdividef(1.0f, q);
            al[j]   += __logf(q);

            float a0 = c0[j] - mur[j];
            float r0 = fmaf(-e, yc[0][j], a0);
            aq[0][j] = fmaf(r0 * r0, iq, aq[0][j]);
            yc[0][j] = a0;

            float a1 = c1[j] - mur[j];
            float r1 = fmaf(-e, yc[1][j], a1);
            aq[1][j] = fmaf(r1 * r1, iq, aq[1][j]);
            yc[1][j] = a1;
        }
        tc = tn; c0 = n0; c1 = n1;
    }

    // ---- reduce: 2 pair sums + 1 logdet sum ----
    float s0 = (aq[0][0] + aq[0][1]) + (aq[0][2] + aq[0][3]);
    float s1 = (aq[1][0] + aq[1][1]) + (aq[1][2] + aq[1][3]);
    float sl = (al[0] + al[1]) + (al[2] + al[3]);
    #pragma unroll
    for (int off = 32; off > 0; off >>= 1) {
        s0 += __shfl_down(s0, off);
        s1 += __shfl_down(s1, off);
        sl += __shfl_down(sl, off);
    }

    __shared__ float w[3][4];
    if (lane == 0) {
        w[0][widx] = s0; w[1][widx] = s1; w[2][widx] = sl;
    }
    __syncthreads();
    if (threadIdx.x == 0) {
        float A0 = (w[0][0] + w[0][1]) + (w[0][2] + w[0][3]);
        float A1 = (w[1][0] + w[1][1]) + (w[1][2] + w[1][3]);
        float AL = (w[2][0] + w[2][1]) + (w[2][2] + w[2][3]);
        // analytic LOG2PI: this block covered t in [lo_b, hi_b) plus
        // (block 0 only) the D lp0 terms.
        const int lo_b = 1 + (NT * (blockIdx.x * 4)) / NW;
        const int hi_b = 1 + (NT * (blockIdx.x * 4 + 4)) / NW;
        int terms = (hi_b - lo_b) * D + (blockIdx.x == 0 ? D : 0);
        AL += LOG2PI * (float)terms;
        atomicAdd(out + bp + 0, -0.5f * (A0 + AL));
        atomicAdd(out + bp + 1, -0.5f * (A1 + AL));
    }
}

extern "C" void kernel_launch(void* const* d_in, const int* in_sizes, int n_in,
                              void* d_out, int out_size, void* d_ws, size_t ws_size,
                              hipStream_t stream) {
    const float* y  = (const float*)d_in[0];
    const float* ts = (const float*)d_in[1];
    const float* mu = (const float*)d_in[2];
    const float* lk = (const float*)d_in[3];
    const float* ls = (const float*)d_in[4];
    float* out = (float*)d_out;

    const int D = in_sizes[2];               // 256
    const int T = in_sizes[1] / D;           // 1024
    const int B = in_sizes[0] / (T * D);     // 256

    hipMemsetAsync(d_out, 0, (size_t)out_size * sizeof(float), stream);

    dim3 grid(8, B / 2);
    ou_fused2_kernel<<<grid, dim3(256), 0, stream>>>(y, ts, mu, lk, ls, out, B, T, D);
}